// Round 18
// baseline (616.751 us; speedup 1.0000x reference)
//
#include <hip/hip_runtime.h>
#include <math.h>

typedef __attribute__((ext_vector_type(4))) float f32x4;
typedef __attribute__((ext_vector_type(2))) float f32x2;
typedef __attribute__((ext_vector_type(8))) short bf16x8;
typedef __attribute__((ext_vector_type(4))) short short4v;

#define EPSN 1e-12f
#define TN 32
#define A1B 8192        // A1 base (shorts); A0 = [0, 8192)
#define FB  16384       // F region base (shorts), stride FS
#define FS  260
#define IOB 24704       // IOU region base (shorts), stride IS
#define IS  388
#define UTOT 37120      // 74240 B
#define NBLK 512

__device__ inline short f2bf(float x) {
    union { float f; unsigned u; } v; v.f = x;
    unsigned r = v.u + 0x7fffu + ((v.u >> 16) & 1u);
    return (short)(r >> 16);
}
__device__ inline float bf2f(short s) {
    union { unsigned u; float f; } v;
    v.u = ((unsigned)(unsigned short)s) << 16;
    return v.f;
}
__device__ inline float wsum64(float v) {
#pragma unroll
    for (int m = 32; m > 0; m >>= 1) v += __shfl_xor(v, m);
    return v;
}
__device__ inline float wsum32(float v) {
    v += __shfl_xor(v, 1);
    v += __shfl_xor(v, 2);
    v += __shfl_xor(v, 4);
    v += __shfl_xor(v, 8);
    v += __shfl_xor(v, 16);
    return v;
}
__device__ inline float sigm(float x) { return 1.0f / (1.0f + __expf(-x)); }
__device__ inline float tanh_fast(float x) {
    float a = fabsf(x);
    float e = __expf(2.0f * a);
    float t = 1.0f - 2.0f / (e + 1.0f);
    return copysignf(t, x);
}
__device__ inline float dot4(f32x4 v) { return v.x*v.x + v.y*v.y + v.z*v.z + v.w*v.w; }
__device__ inline short4v pack4(f32x4 v) {
    short4v p;
    p.x = f2bf(v.x); p.y = f2bf(v.y); p.z = f2bf(v.z); p.w = f2bf(v.w);
    return p;
}

// ---- prep: W_f (256x256) + W_iou (384x256) -> bf16 fragment-linear B ----
__global__ void prep_B(const float* __restrict__ W_f, const float* __restrict__ W_iou,
                       short* __restrict__ Blin) {
    int t = blockIdx.x * 256 + threadIdx.x;
    if (t >= 8 * 40 * 64) return;
    int lane = t & 63;
    int jb = (t >> 6) % 40;
    int kb = (t >> 6) / 40;
    int j = jb * 16 + (lane & 15);
    int k = kb * 32 + ((lane >> 4) << 3);
    const float* src = (j < 256) ? (W_f + (size_t)j * 256 + k)
                                 : (W_iou + (size_t)(j - 256) * 256 + k);
    bf16x8 v;
#pragma unroll
    for (int e = 0; e < 8; ++e) v[e] = f2bf(src[e]);
    *(bf16x8*)(Blin + (size_t)t * 8) = v;
}

// GEMM pass over a 32x256 A tile (fragment-linear, XOR-swizzled; conflict-free):
// NJJ col-blocks starting at jbase, 2 M-frags. f = kb*128 + kg*32 + row.
template<int NJJ>
__device__ inline void gpass32(const short* __restrict__ A, const short* __restrict__ Blin,
                               int lane, int jbase, f32x4 acc[2][NJJ]) {
    const int la = lane & 15, kg = lane >> 4;
#pragma unroll
    for (int kb = 0; kb < 8; ++kb) {
        bf16x8 af[2];
#pragma unroll
        for (int m = 0; m < 2; ++m) {
            const int f = kb * 128 + kg * 32 + m * 16 + la;
            af[m] = *(const bf16x8*)&A[(f ^ ((f >> 5) & 7)) << 3];
        }
#pragma unroll
        for (int jj = 0; jj < NJJ; ++jj) {
            const bf16x8 b = *(const bf16x8*)(Blin +
                ((size_t)((kb * 40 + jbase + jj) * 64 + lane)) * 8);
            acc[0][jj] = __builtin_amdgcn_mfma_f32_16x16x32_bf16(af[0], b, acc[0][jj], 0, 0, 0);
            acc[1][jj] = __builtin_amdgcn_mfma_f32_16x16x32_bf16(af[1], b, acc[1][jj], 0, 0, 0);
        }
    }
}

// ---- fused, persistent, cross-tile pipelined; TN=32; (512,4) — no forced cliff ----
__global__ __launch_bounds__(512, 4) void tree_fused(
    const float* __restrict__ h_src, const float* __restrict__ c_src,
    const float* __restrict__ iou, const int* __restrict__ child_idx,
    const float* __restrict__ b_f, const float* __restrict__ b_iou,
    const float* __restrict__ sc_iou_p, const float* __restrict__ sc_c_p,
    const short* __restrict__ Blin, float* __restrict__ out, int ntiles) {
    __shared__ __align__(16) short U[UTOT];
    __shared__ float h_n2[2][TN], iou_n2[2][TN];
    __shared__ int cc_lds[2][TN][2];

    const int tid = threadIdx.x;
    const int wave = tid >> 6;
    const int lane = tid & 63;
    const int la = lane & 15, kg = lane >> 4;
    const int G = gridDim.x;

    const float sc_iou = sc_iou_p[0];
    const float sc_c = sc_c_p[0];

    const int child = lane >> 5;
    const int seg = lane & 31;

    // epilogue mapping: 32 threads/node, 4 elems; two 16-node halves
    const int nd0 = tid >> 5;
    const int q = tid & 31;
    const int h0q = q * 4;

    // b_f fold values (constant per thread)
    const float bf0 = b_f[(wave * 2 + 0) * 16 + la];
    const float bf1 = b_f[(wave * 2 + 1) * 16 + la];

    const int t0 = blockIdx.x;
    if (t0 >= ntiles) return;

    int idxA[4];

    // ---------- prologue: stage tile t0 into buffer 0; prefetch idx(t0+G) ----------
    {
        int cix[4];
#pragma unroll
        for (int r = 0; r < 4; ++r)
            cix[r] = child_idx[(size_t)(t0 * TN + wave + 8 * r) * 2 + child];
#pragma unroll
        for (int half = 0; half < 2; ++half) {
            f32x4 hv[2], v4[2];
            f32x2 v2[2];
#pragma unroll
            for (int rr = 0; rr < 2; ++rr) {
                const int r = half * 2 + rr;
                const size_t node = (size_t)t0 * TN + wave + 8 * r;
                hv[rr] = *(const f32x4*)(h_src + (size_t)cix[r] * 128 + seg * 4);
                v4[rr] = *(const f32x4*)(iou + node * 384 + lane * 4);
                v2[rr] = *(const f32x2*)(iou + node * 384 + 256 + lane * 2);
            }
#pragma unroll
            for (int rr = 0; rr < 2; ++rr) {
                const int r = half * 2 + rr;
                const int nd = wave + 8 * r;
                const int f = (child * 4 + (seg >> 3)) * 128 + ((seg >> 1) & 3) * 32 + nd;
                const int addr = ((f ^ ((f >> 5) & 7)) << 3) + (seg & 1) * 4;
                *(short4v*)&U[addr] = pack4(hv[rr]);
                if (lane == 0) cc_lds[0][nd][0] = cix[r];
                if (lane == 32) cc_lds[0][nd][1] = cix[r];
                float hss = wsum64(dot4(hv[rr]));
                float iss = wsum64(dot4(v4[rr]) + v2[rr].x * v2[rr].x + v2[rr].y * v2[rr].y);
                if (lane == 0) { h_n2[0][nd] = hss; iou_n2[0][nd] = iss; }
            }
            __builtin_amdgcn_sched_barrier(0);
        }
        if (t0 + G < ntiles) {
#pragma unroll
            for (int r = 0; r < 4; ++r)
                idxA[r] = child_idx[(size_t)((t0 + G) * TN + wave + 8 * r) * 2 + child];
        }
    }
    __syncthreads();   // B0: buffer-0 staging visible

    int b = 0;
    for (int t = t0; t < ntiles; t += G, b ^= 1) {
        const int nt = t + G;
        const bool hn = nt < ntiles;
        const int Ab = b * A1B;
        const int An = A1B - Ab;

        // ---- issue next-tile h gathers (fly under both GEMMs) ----
        f32x4 hvn[4];
        if (hn) {
#pragma unroll
            for (int r = 0; r < 4; ++r)
                hvn[r] = *(const f32x4*)(h_src + (size_t)idxA[r] * 128 + seg * 4);
        }

        // ---- c prefetch half 0 (bf16-packed, fp32 norm) ----
        short4v c0a, c1a;
        float n2a;
        {
            const int c00 = cc_lds[b][nd0][0];
            const int c01 = cc_lds[b][nd0][1];
            const f32x4 p0 = *(const f32x4*)(c_src + (size_t)c00 * 128 + h0q);
            const f32x4 p1 = *(const f32x4*)(c_src + (size_t)c01 * 128 + h0q);
            n2a = dot4(p0);
            c0a = pack4(p0);
            c1a = pack4(p1);
        }

        // ---------- GEMM-F: cols 0..255, b_f folded; spill to F region ----------
        {
            f32x4 accf[2][2];
            accf[0][0] = (f32x4){bf0, bf0, bf0, bf0};
            accf[1][0] = accf[0][0];
            accf[0][1] = (f32x4){bf1, bf1, bf1, bf1};
            accf[1][1] = accf[0][1];
            gpass32<2>(&U[Ab], Blin, lane, wave * 2, accf);
#pragma unroll
            for (int m = 0; m < 2; ++m)
#pragma unroll
                for (int jj = 0; jj < 2; ++jj) {
                    const int col = (wave * 2 + jj) * 16 + la;
#pragma unroll
                    for (int r = 0; r < 4; ++r) {
                        const int row = m * 16 + kg * 4 + r;
                        U[FB + row * FS + col] = f2bf(accf[m][jj][r]);
                    }
                }
        }

        // ---- c prefetch half 1 ----
        short4v c0b, c1b;
        float n2b;
        {
            const int c10 = cc_lds[b][16 + nd0][0];
            const int c11 = cc_lds[b][16 + nd0][1];
            const f32x4 p0 = *(const f32x4*)(c_src + (size_t)c10 * 128 + h0q);
            const f32x4 p1 = *(const f32x4*)(c_src + (size_t)c11 * 128 + h0q);
            n2b = dot4(p0);
            c0b = pack4(p0);
            c1b = pack4(p1);
        }
        __syncthreads();   // BAR-1: F visible

        // ---------- part 1: forget gates + weighted cell sum ----------
        float csr[2][4], s_v[2];
#pragma unroll
        for (int p = 0; p < 2; ++p) {
            const int nd = p * 16 + nd0;
            const short4v c0v = p ? c0b : c0a;
            const short4v c1v = p ? c1b : c1a;
            const short4v yf0 = *(const short4v*)&U[FB + nd * FS + h0q];
            const short4v yf1 = *(const short4v*)&U[FB + nd * FS + 128 + h0q];
            float c0n2 = wsum32(p ? n2b : n2a);
            float cs[4];
            float csn2 = 0.f;
#pragma unroll
            for (int e = 0; e < 4; ++e) {
                const float f0 = sigm(bf2f(yf0[e]));   // b_f folded into Y
                const float f1 = sigm(bf2f(yf1[e]));
                const float v = f0 * bf2f(c0v[e]) + f1 * bf2f(c1v[e]);
                cs[e] = v;
                csn2 += v * v;
            }
            csn2 = wsum32(csn2);
            const float rs = sc_c * sqrtf(c0n2) / fmaxf(sqrtf(csn2), EPSN);
#pragma unroll
            for (int e = 0; e < 4; ++e) csr[p][e] = cs[e] * rs;
            s_v[p] = sc_iou * sqrtf(iou_n2[b][nd]) / fmaxf(sqrtf(h_n2[b][nd]), EPSN);
        }

        // ---------- stage tile t+1 into A[b^1] (iou loads + A writes + norms) ----------
        if (hn) {
#pragma unroll
            for (int half = 0; half < 2; ++half) {
                f32x4 v4[2];
                f32x2 v2[2];
#pragma unroll
                for (int rr = 0; rr < 2; ++rr) {
                    const int r = half * 2 + rr;
                    const size_t node = (size_t)nt * TN + wave + 8 * r;
                    v4[rr] = *(const f32x4*)(iou + node * 384 + lane * 4);
                    v2[rr] = *(const f32x2*)(iou + node * 384 + 256 + lane * 2);
                }
#pragma unroll
                for (int rr = 0; rr < 2; ++rr) {
                    const int r = half * 2 + rr;
                    const int nd = wave + 8 * r;
                    const int f = (child * 4 + (seg >> 3)) * 128 + ((seg >> 1) & 3) * 32 + nd;
                    const int addr = An + ((f ^ ((f >> 5) & 7)) << 3) + (seg & 1) * 4;
                    *(short4v*)&U[addr] = pack4(hvn[r]);
                    if (lane == 0) cc_lds[b ^ 1][nd][0] = idxA[r];
                    if (lane == 32) cc_lds[b ^ 1][nd][1] = idxA[r];
                    float hss = wsum64(dot4(hvn[r]));
                    float iss = wsum64(dot4(v4[rr]) + v2[rr].x * v2[rr].x + v2[rr].y * v2[rr].y);
                    if (lane == 0) { h_n2[b ^ 1][nd] = hss; iou_n2[b ^ 1][nd] = iss; }
                }
            }
        }
        if (nt + G < ntiles) {
#pragma unroll
            for (int r = 0; r < 4; ++r)
                idxA[r] = child_idx[(size_t)((nt + G) * TN + wave + 8 * r) * 2 + child];
        }

        // ---------- GEMM-IOU: cols 256..639; spill to IOU region ----------
        {
            f32x4 accio[2][3];
#pragma unroll
            for (int m = 0; m < 2; ++m)
#pragma unroll
                for (int jj = 0; jj < 3; ++jj) accio[m][jj] = (f32x4){0.f, 0.f, 0.f, 0.f};
            gpass32<3>(&U[Ab], Blin, lane, 16 + wave * 3, accio);
#pragma unroll
            for (int m = 0; m < 2; ++m)
#pragma unroll
                for (int jj = 0; jj < 3; ++jj) {
                    const int col = (wave * 3 + jj) * 16 + la;
#pragma unroll
                    for (int r = 0; r < 4; ++r) {
                        const int row = m * 16 + kg * 4 + r;
                        U[IOB + row * IS + col] = f2bf(accio[m][jj][r]);
                    }
                }
        }
        __syncthreads();   // BAR-2: IOU staging + A[b^1] staging visible; A[b]/F reads done

        // ---------- part 2: i/o/u gates -> h, c ----------
        {
            const f32x4 bi0 = *(const f32x4*)(b_iou + h0q);
            const f32x4 bi1 = *(const f32x4*)(b_iou + 128 + h0q);
            const f32x4 bi2 = *(const f32x4*)(b_iou + 256 + h0q);
#pragma unroll
            for (int p = 0; p < 2; ++p) {
                const int nd = p * 16 + nd0;
                const size_t node = (size_t)t * TN + nd;
                const short4v yi = *(const short4v*)&U[IOB + nd * IS + h0q];
                const short4v yo = *(const short4v*)&U[IOB + nd * IS + 128 + h0q];
                const short4v yu = *(const short4v*)&U[IOB + nd * IS + 256 + h0q];
                f32x4 outh, outc;
#pragma unroll
                for (int e = 0; e < 4; ++e) {
                    const float iv = bf2f(yi[e]) * s_v[p] + ((const float*)&bi0)[e];
                    const float ov = bf2f(yo[e]) * s_v[p] + ((const float*)&bi1)[e];
                    const float uv = bf2f(yu[e]) * s_v[p] + ((const float*)&bi2)[e];
                    const float cval = sigm(iv) * tanh_fast(uv) + csr[p][e];
                    const float hval = sigm(ov) * tanh_fast(cval);
                    ((float*)&outh)[e] = hval;
                    ((float*)&outc)[e] = cval;
                }
                *(f32x4*)(out + node * 256 + h0q) = outh;
                *(f32x4*)(out + node * 256 + 128 + h0q) = outc;
            }
        }
    }
}

extern "C" void kernel_launch(void* const* d_in, const int* in_sizes, int n_in,
                              void* d_out, int out_size, void* d_ws, size_t ws_size,
                              hipStream_t stream) {
    const float* h_src = (const float*)d_in[0];
    const float* c_src = (const float*)d_in[1];
    const float* iou = (const float*)d_in[2];
    const int* cidx = (const int*)d_in[3];
    const float* W_f = (const float*)d_in[4];
    const float* b_f = (const float*)d_in[5];
    const float* W_iou = (const float*)d_in[6];
    const float* b_iou = (const float*)d_in[7];
    const float* s_iou = (const float*)d_in[8];
    const float* s_c = (const float*)d_in[9];
    float* out = (float*)d_out;
    short* Blin = (short*)d_ws;

    const int N = in_sizes[3] / 2;        // 200000
    const int ntiles = N / TN;            // 6250
    const int grid = (ntiles < NBLK) ? ntiles : NBLK;
    hipLaunchKernelGGL(prep_B, dim3(80), dim3(256), 0, stream, W_f, W_iou, Blin);
    hipLaunchKernelGGL(tree_fused, dim3(grid), dim3(512), 0, stream,
                       h_src, c_src, iou, cidx, b_f, b_iou, s_iou, s_c, Blin, out, ntiles);
}

// Round 19
// 263.999 us; speedup vs baseline: 2.3362x; 2.3362x over previous
//
#include <hip/hip_runtime.h>
#include <math.h>

typedef __attribute__((ext_vector_type(4))) float f32x4;
typedef __attribute__((ext_vector_type(2))) float f32x2;
typedef __attribute__((ext_vector_type(8))) short bf16x8;
typedef __attribute__((ext_vector_type(4))) short short4v;

#define EPSN 1e-12f
#define TN 32
#define FS 260          // F region row stride (shorts), measured conflict-free
#define IS 388          // IOU region row stride (shorts), measured conflict-free
#define FBASE 8192      // F region base; A = [0, 8192)
#define IOB 16512       // IOU region base (8192 + 32*260)
#define UTOT 28928      // 16512 + 32*388 shorts = 57856 B (2 blocks/CU: 115.7 KB <= 160)

__device__ inline short f2bf(float x) {
    union { float f; unsigned u; } v; v.f = x;
    unsigned r = v.u + 0x7fffu + ((v.u >> 16) & 1u);
    return (short)(r >> 16);
}
__device__ inline float bf2f(short s) {
    union { unsigned u; float f; } v;
    v.u = ((unsigned)(unsigned short)s) << 16;
    return v.f;
}
__device__ inline float wsum64(float v) {
#pragma unroll
    for (int m = 32; m > 0; m >>= 1) v += __shfl_xor(v, m);
    return v;
}
__device__ inline float wsum32(float v) {
    v += __shfl_xor(v, 1);
    v += __shfl_xor(v, 2);
    v += __shfl_xor(v, 4);
    v += __shfl_xor(v, 8);
    v += __shfl_xor(v, 16);
    return v;
}
__device__ inline float sigm(float x) { return 1.0f / (1.0f + __expf(-x)); }
__device__ inline float tanh_fast(float x) {
    float a = fabsf(x);
    float e = __expf(2.0f * a);
    float t = 1.0f - 2.0f / (e + 1.0f);
    return copysignf(t, x);
}
__device__ inline float dot4(f32x4 v) { return v.x*v.x + v.y*v.y + v.z*v.z + v.w*v.w; }
__device__ inline short4v pack4(f32x4 v) {
    short4v p;
    p.x = f2bf(v.x); p.y = f2bf(v.y); p.z = f2bf(v.z); p.w = f2bf(v.w);
    return p;
}

// ---- prep: W_f (256x256) + W_iou (384x256) -> bf16 fragment-linear B ----
__global__ void prep_B(const float* __restrict__ W_f, const float* __restrict__ W_iou,
                       short* __restrict__ Blin) {
    int t = blockIdx.x * 256 + threadIdx.x;
    if (t >= 8 * 40 * 64) return;
    int lane = t & 63;
    int jb = (t >> 6) % 40;
    int kb = (t >> 6) / 40;
    int j = jb * 16 + (lane & 15);
    int k = kb * 32 + ((lane >> 4) << 3);
    const float* src = (j < 256) ? (W_f + (size_t)j * 256 + k)
                                 : (W_iou + (size_t)(j - 256) * 256 + k);
    bf16x8 v;
#pragma unroll
    for (int e = 0; e < 8; ++e) v[e] = f2bf(src[e]);
    *(bf16x8*)(Blin + (size_t)t * 8) = v;
}

// GEMM pass over 32x256 A tile (fragment-linear chunks, XOR-swizzled): NJJ
// col-blocks starting at jbase, 2 M-frags. Fragment index f = kb*128 + kg*32 + row.
template<int NJJ>
__device__ inline void gpass32(const short* __restrict__ A, const short* __restrict__ Blin,
                               int lane, int jbase, f32x4 acc[2][NJJ]) {
    const int la = lane & 15, kg = lane >> 4;
#pragma unroll
    for (int kb = 0; kb < 8; ++kb) {
        bf16x8 af[2];
#pragma unroll
        for (int m = 0; m < 2; ++m) {
            const int f = kb * 128 + kg * 32 + m * 16 + la;
            af[m] = *(const bf16x8*)&A[(f ^ ((f >> 5) & 7)) << 3];
        }
#pragma unroll
        for (int jj = 0; jj < NJJ; ++jj) {
            const bf16x8 b = *(const bf16x8*)(Blin +
                ((size_t)((kb * 40 + jbase + jj) * 64 + lane)) * 8);
            acc[0][jj] = __builtin_amdgcn_mfma_f32_16x16x32_bf16(af[0], b, acc[0][jj], 0, 0, 0);
            acc[1][jj] = __builtin_amdgcn_mfma_f32_16x16x32_bf16(af[1], b, acc[1][jj], 0, 0, 0);
        }
    }
}

// ---- fused: TN=32, disjoint LDS regions, only TWO barriers per tile ----
__global__ __launch_bounds__(512, 4) void tree_fused(
    const float* __restrict__ h_src, const float* __restrict__ c_src,
    const float* __restrict__ iou, const int* __restrict__ child_idx,
    const float* __restrict__ b_f, const float* __restrict__ b_iou,
    const float* __restrict__ sc_iou_p, const float* __restrict__ sc_c_p,
    const short* __restrict__ Blin, float* __restrict__ out) {
    __shared__ __align__(16) short U[UTOT];
    __shared__ float h_n2[TN], iou_n2[TN];
    __shared__ int cc_lds[TN][2];

    const int tid = threadIdx.x;
    const int wave = tid >> 6;
    const int lane = tid & 63;
    const int la = lane & 15, kg = lane >> 4;
    const size_t nb0 = (size_t)blockIdx.x * TN;

    const float sc_iou = sc_iou_p[0];
    const float sc_c = sc_c_p[0];

    // ---------- phase 1: idx -> h gather -> A; h/iou norms (2 nodes at a time) ----------
    {
        const int child = lane >> 5;
        const int seg = lane & 31;
        int cix[4];
#pragma unroll
        for (int r = 0; r < 4; ++r)
            cix[r] = child_idx[(size_t)(nb0 + wave + 8 * r) * 2 + child];
#pragma unroll
        for (int half = 0; half < 2; ++half) {
            f32x4 hv[2], v4[2];
            f32x2 v2[2];
#pragma unroll
            for (int rr = 0; rr < 2; ++rr) {
                const int r = half * 2 + rr;
                const size_t node = nb0 + wave + 8 * r;
                hv[rr] = *(const f32x4*)(h_src + (size_t)cix[r] * 128 + seg * 4);
                v4[rr] = *(const f32x4*)(iou + node * 384 + lane * 4);
                v2[rr] = *(const f32x2*)(iou + node * 384 + 256 + lane * 2);
            }
#pragma unroll
            for (int rr = 0; rr < 2; ++rr) {
                const int r = half * 2 + rr;
                const int nd = wave + 8 * r;
                // kfull = child*128 + seg*4 -> kb = child*4 + (seg>>3), kg = (seg>>1)&3
                const int f = (child * 4 + (seg >> 3)) * 128 + ((seg >> 1) & 3) * 32 + nd;
                const int addr = ((f ^ ((f >> 5) & 7)) << 3) + (seg & 1) * 4;
                *(short4v*)&U[addr] = pack4(hv[rr]);
                if (lane == 0) cc_lds[nd][0] = cix[r];
                if (lane == 32) cc_lds[nd][1] = cix[r];
                float hss = wsum64(dot4(hv[rr]));
                float iss = wsum64(dot4(v4[rr]) + v2[rr].x * v2[rr].x + v2[rr].y * v2[rr].y);
                if (lane == 0) { h_n2[nd] = hss; iou_n2[nd] = iss; }
            }
            __builtin_amdgcn_sched_barrier(0);   // keep half-B loads from hoisting
        }
    }
    __syncthreads();   // B1: A + cc_lds + norms visible

    // epilogue mapping: 32 threads/node, 4 elems; two 16-node halves
    const int nd0 = tid >> 5;          // 0..15
    const int q = tid & 31;
    const int h0q = q * 4;

    // ---- c prefetch, BOTH halves (fly under both GEMMs; bf16-packed, fp32 norm) ----
    short4v c0a, c1a, c0b, c1b;
    float n2a, n2b;
    {
        const int c00 = cc_lds[nd0][0];
        const int c01 = cc_lds[nd0][1];
        const int c10 = cc_lds[16 + nd0][0];
        const int c11 = cc_lds[16 + nd0][1];
        const f32x4 t0 = *(const f32x4*)(c_src + (size_t)c00 * 128 + h0q);
        const f32x4 t1 = *(const f32x4*)(c_src + (size_t)c01 * 128 + h0q);
        const f32x4 t2 = *(const f32x4*)(c_src + (size_t)c10 * 128 + h0q);
        const f32x4 t3 = *(const f32x4*)(c_src + (size_t)c11 * 128 + h0q);
        n2a = dot4(t0);
        n2b = dot4(t2);
        c0a = pack4(t0); c1a = pack4(t1);
        c0b = pack4(t2); c1b = pack4(t3);
    }

    // ---------- GEMM-F: cols 0..255, b_f folded; spill to F region ----------
    {
        f32x4 accf[2][2];
        const float bf0 = b_f[(wave * 2 + 0) * 16 + la];
        const float bf1 = b_f[(wave * 2 + 1) * 16 + la];
        accf[0][0] = (f32x4){bf0, bf0, bf0, bf0};
        accf[1][0] = accf[0][0];
        accf[0][1] = (f32x4){bf1, bf1, bf1, bf1};
        accf[1][1] = accf[0][1];
        gpass32<2>(U, Blin, lane, wave * 2, accf);
#pragma unroll
        for (int m = 0; m < 2; ++m)
#pragma unroll
            for (int jj = 0; jj < 2; ++jj) {
                const int col = (wave * 2 + jj) * 16 + la;
#pragma unroll
                for (int r = 0; r < 4; ++r) {
                    const int row = m * 16 + kg * 4 + r;
                    U[FBASE + row * FS + col] = f2bf(accf[m][jj][r]);
                }
            }
    }

    // ---------- GEMM-IOU: cols 256..639; spill to its own region ----------
    {
        f32x4 accio[2][3];
#pragma unroll
        for (int m = 0; m < 2; ++m)
#pragma unroll
            for (int jj = 0; jj < 3; ++jj) accio[m][jj] = (f32x4){0.f, 0.f, 0.f, 0.f};
        gpass32<3>(U, Blin, lane, 16 + wave * 3, accio);
#pragma unroll
        for (int m = 0; m < 2; ++m)
#pragma unroll
            for (int jj = 0; jj < 3; ++jj) {
                const int col = (wave * 3 + jj) * 16 + la;   // 0..383 = i|o|u
#pragma unroll
                for (int r = 0; r < 4; ++r) {
                    const int row = m * 16 + kg * 4 + r;
                    U[IOB + row * IS + col] = f2bf(accio[m][jj][r]);
                }
            }
    }
    __syncthreads();   // B2: F + IOU staging visible (single post-GEMM barrier)

    // ---------- merged epilogue: forget gates + cell sum + i/o/u -> h, c ----------
    const f32x4 bi0 = *(const f32x4*)(b_iou + h0q);
    const f32x4 bi1 = *(const f32x4*)(b_iou + 128 + h0q);
    const f32x4 bi2 = *(const f32x4*)(b_iou + 256 + h0q);
#pragma unroll
    for (int p = 0; p < 2; ++p) {
        const int nd = p * 16 + nd0;
        const size_t node = nb0 + nd;
        const short4v c0v = p ? c0b : c0a;
        const short4v c1v = p ? c1b : c1a;
        const short4v yf0 = *(const short4v*)&U[FBASE + nd * FS + h0q];
        const short4v yf1 = *(const short4v*)&U[FBASE + nd * FS + 128 + h0q];
        float c0n2 = wsum32(p ? n2b : n2a);
        float cs[4];
        float csn2 = 0.f;
#pragma unroll
        for (int e = 0; e < 4; ++e) {
            const float f0 = sigm(bf2f(yf0[e]));   // b_f folded into Y
            const float f1 = sigm(bf2f(yf1[e]));
            const float v = f0 * bf2f(c0v[e]) + f1 * bf2f(c1v[e]);
            cs[e] = v;
            csn2 += v * v;
        }
        csn2 = wsum32(csn2);
        const float rs = sc_c * sqrtf(c0n2) / fmaxf(sqrtf(csn2), EPSN);
        const float s_v = sc_iou * sqrtf(iou_n2[nd]) / fmaxf(sqrtf(h_n2[nd]), EPSN);

        const short4v yi = *(const short4v*)&U[IOB + nd * IS + h0q];
        const short4v yo = *(const short4v*)&U[IOB + nd * IS + 128 + h0q];
        const short4v yu = *(const short4v*)&U[IOB + nd * IS + 256 + h0q];
        f32x4 outh, outc;
#pragma unroll
        for (int e = 0; e < 4; ++e) {
            const float iv = bf2f(yi[e]) * s_v + ((const float*)&bi0)[e];
            const float ov = bf2f(yo[e]) * s_v + ((const float*)&bi1)[e];
            const float uv = bf2f(yu[e]) * s_v + ((const float*)&bi2)[e];
            const float cval = sigm(iv) * tanh_fast(uv) + cs[e] * rs;
            const float hval = sigm(ov) * tanh_fast(cval);
            ((float*)&outh)[e] = hval;
            ((float*)&outc)[e] = cval;
        }
        *(f32x4*)(out + node * 256 + h0q) = outh;
        *(f32x4*)(out + node * 256 + 128 + h0q) = outc;
    }
}

extern "C" void kernel_launch(void* const* d_in, const int* in_sizes, int n_in,
                              void* d_out, int out_size, void* d_ws, size_t ws_size,
                              hipStream_t stream) {
    const float* h_src = (const float*)d_in[0];
    const float* c_src = (const float*)d_in[1];
    const float* iou = (const float*)d_in[2];
    const int* cidx = (const int*)d_in[3];
    const float* W_f = (const float*)d_in[4];
    const float* b_f = (const float*)d_in[5];
    const float* W_iou = (const float*)d_in[6];
    const float* b_iou = (const float*)d_in[7];
    const float* s_iou = (const float*)d_in[8];
    const float* s_c = (const float*)d_in[9];
    float* out = (float*)d_out;
    short* Blin = (short*)d_ws;

    const int N = in_sizes[3] / 2;        // 200000
    const int ntiles = N / TN;            // 6250
    hipLaunchKernelGGL(prep_B, dim3(80), dim3(256), 0, stream, W_f, W_iou, Blin);
    hipLaunchKernelGGL(tree_fused, dim3(ntiles), dim3(512), 0, stream,
                       h_src, c_src, iou, cidx, b_f, b_iou, s_iou, s_c, Blin, out);
}

// Round 20
// 236.217 us; speedup vs baseline: 2.6110x; 1.1176x over previous
//
#include <hip/hip_runtime.h>
#include <math.h>

typedef __attribute__((ext_vector_type(4))) float f32x4;
typedef __attribute__((ext_vector_type(2))) float f32x2;
typedef __attribute__((ext_vector_type(8))) short bf16x8;
typedef __attribute__((ext_vector_type(4))) short short4v;

#define EPSN 1e-12f
#define TN 32
#define FS 260          // F region row stride (shorts): kg/r bank-offsets disjoint
#define IS 388          // IOU region row stride (shorts), same property
#define FBASE 8192      // F region base (shorts); A = [0, 8192)
#define UTOT 16512      // 8192 + 32*260 shorts = 33024 B

__device__ inline short f2bf(float x) {
    union { float f; unsigned u; } v; v.f = x;
    unsigned r = v.u + 0x7fffu + ((v.u >> 16) & 1u);
    return (short)(r >> 16);
}
__device__ inline float bf2f(short s) {
    union { unsigned u; float f; } v;
    v.u = ((unsigned)(unsigned short)s) << 16;
    return v.f;
}
__device__ inline float wsum64(float v) {
#pragma unroll
    for (int m = 32; m > 0; m >>= 1) v += __shfl_xor(v, m);
    return v;
}
__device__ inline float wsum32(float v) {
    v += __shfl_xor(v, 1);
    v += __shfl_xor(v, 2);
    v += __shfl_xor(v, 4);
    v += __shfl_xor(v, 8);
    v += __shfl_xor(v, 16);
    return v;
}
__device__ inline float sigm(float x) { return 1.0f / (1.0f + __expf(-x)); }
__device__ inline float tanh_fast(float x) {
    float a = fabsf(x);
    float e = __expf(2.0f * a);
    float t = 1.0f - 2.0f / (e + 1.0f);
    return copysignf(t, x);
}
__device__ inline float dot4(f32x4 v) { return v.x*v.x + v.y*v.y + v.z*v.z + v.w*v.w; }
__device__ inline short4v pack4(f32x4 v) {
    short4v p;
    p.x = f2bf(v.x); p.y = f2bf(v.y); p.z = f2bf(v.z); p.w = f2bf(v.w);
    return p;
}

// ---- prep: W_f (256x256) + W_iou (384x256) -> bf16 fragment-linear B ----
__global__ void prep_B(const float* __restrict__ W_f, const float* __restrict__ W_iou,
                       short* __restrict__ Blin) {
    int t = blockIdx.x * 256 + threadIdx.x;
    if (t >= 8 * 40 * 64) return;
    int lane = t & 63;
    int jb = (t >> 6) % 40;
    int kb = (t >> 6) / 40;
    int j = jb * 16 + (lane & 15);
    int k = kb * 32 + ((lane >> 4) << 3);
    const float* src = (j < 256) ? (W_f + (size_t)j * 256 + k)
                                 : (W_iou + (size_t)(j - 256) * 256 + k);
    bf16x8 v;
#pragma unroll
    for (int e = 0; e < 8; ++e) v[e] = f2bf(src[e]);
    *(bf16x8*)(Blin + (size_t)t * 8) = v;
}

// GEMM pass over 32x256 A tile (fragment-linear chunks, XOR-swizzled): NJJ
// col-blocks starting at jbase, 2 M-frags. Fragment index f = kb*128 + kg*32 + row.
template<int NJJ>
__device__ inline void gpass32(const short* __restrict__ A, const short* __restrict__ Blin,
                               int lane, int jbase, f32x4 acc[2][NJJ]) {
    const int la = lane & 15, kg = lane >> 4;
#pragma unroll
    for (int kb = 0; kb < 8; ++kb) {
        bf16x8 af[2];
#pragma unroll
        for (int m = 0; m < 2; ++m) {
            const int f = kb * 128 + kg * 32 + m * 16 + la;
            af[m] = *(const bf16x8*)&A[(f ^ ((f >> 5) & 7)) << 3];
        }
#pragma unroll
        for (int jj = 0; jj < NJJ; ++jj) {
            const bf16x8 b = *(const bf16x8*)(Blin +
                ((size_t)((kb * 40 + jbase + jj) * 64 + lane)) * 8);
            acc[0][jj] = __builtin_amdgcn_mfma_f32_16x16x32_bf16(af[0], b, acc[0][jj], 0, 0, 0);
            acc[1][jj] = __builtin_amdgcn_mfma_f32_16x16x32_bf16(af[1], b, acc[1][jj], 0, 0, 0);
        }
    }
}

// ---- fused: TN=32, N-split GEMM, c-gathers hidden; nt streams for iou/out ----
__global__ __launch_bounds__(512, 4) void tree_fused(
    const float* __restrict__ h_src, const float* __restrict__ c_src,
    const float* __restrict__ iou, const int* __restrict__ child_idx,
    const float* __restrict__ b_f, const float* __restrict__ b_iou,
    const float* __restrict__ sc_iou_p, const float* __restrict__ sc_c_p,
    const short* __restrict__ Blin, float* __restrict__ out) {
    __shared__ __align__(16) short U[UTOT];
    __shared__ float h_n2[TN], iou_n2[TN];
    __shared__ int cc_lds[TN][2];

    const int tid = threadIdx.x;
    const int wave = tid >> 6;
    const int lane = tid & 63;
    const int la = lane & 15, kg = lane >> 4;
    const size_t nb0 = (size_t)blockIdx.x * TN;

    const float sc_iou = sc_iou_p[0];
    const float sc_c = sc_c_p[0];

    // ---------- phase 1: idx -> h gather -> A; h/iou norms (2 nodes at a time) ----------
    {
        const int child = lane >> 5;
        const int seg = lane & 31;
        int cix[4];
#pragma unroll
        for (int r = 0; r < 4; ++r)
            cix[r] = child_idx[(size_t)(nb0 + wave + 8 * r) * 2 + child];
#pragma unroll
        for (int half = 0; half < 2; ++half) {
            f32x4 hv[2], v4[2];
            f32x2 v2[2];
#pragma unroll
            for (int rr = 0; rr < 2; ++rr) {
                const int r = half * 2 + rr;
                const size_t node = nb0 + wave + 8 * r;
                hv[rr] = *(const f32x4*)(h_src + (size_t)cix[r] * 128 + seg * 4);
                // iou is streamed exactly once -> nontemporal (don't pollute L2/L3)
                v4[rr] = __builtin_nontemporal_load(
                    (const f32x4*)(iou + node * 384 + lane * 4));
                v2[rr] = __builtin_nontemporal_load(
                    (const f32x2*)(iou + node * 384 + 256 + lane * 2));
            }
#pragma unroll
            for (int rr = 0; rr < 2; ++rr) {
                const int r = half * 2 + rr;
                const int nd = wave + 8 * r;
                // kfull = child*128 + seg*4 -> kb = child*4 + (seg>>3), kgf = (seg>>1)&3
                const int f = (child * 4 + (seg >> 3)) * 128 + ((seg >> 1) & 3) * 32 + nd;
                const int addr = ((f ^ ((f >> 5) & 7)) << 3) + (seg & 1) * 4;
                *(short4v*)&U[addr] = pack4(hv[rr]);
                if (lane == 0) cc_lds[nd][0] = cix[r];
                if (lane == 32) cc_lds[nd][1] = cix[r];
                float hss = wsum64(dot4(hv[rr]));
                float iss = wsum64(dot4(v4[rr]) + v2[rr].x * v2[rr].x + v2[rr].y * v2[rr].y);
                if (lane == 0) { h_n2[nd] = hss; iou_n2[nd] = iss; }
            }
            __builtin_amdgcn_sched_barrier(0);   // keep half-B loads from hoisting
        }
    }
    __syncthreads();   // B1: A + cc_lds + norms visible

    // epilogue mapping: 32 threads/node, 4 elems; two 16-node halves
    const int nd0 = tid >> 5;          // 0..15
    const int q = tid & 31;
    const int h0q = q * 4;

    // ---- c prefetch half 0 (flies under both GEMMs; bf16-packed, fp32 norm) ----
    short4v c0a, c1a;
    float n2a;
    {
        const int c00 = cc_lds[nd0][0];
        const int c01 = cc_lds[nd0][1];
        const f32x4 t0 = *(const f32x4*)(c_src + (size_t)c00 * 128 + h0q);
        const f32x4 t1 = *(const f32x4*)(c_src + (size_t)c01 * 128 + h0q);
        n2a = dot4(t0);
        c0a = pack4(t0);
        c1a = pack4(t1);
    }

    // ---------- GEMM-F: cols 0..255, b_f folded ----------
    {
        f32x4 accf[2][2];
        const float bf0 = b_f[(wave * 2 + 0) * 16 + la];
        const float bf1 = b_f[(wave * 2 + 1) * 16 + la];
        accf[0][0] = (f32x4){bf0, bf0, bf0, bf0};
        accf[1][0] = accf[0][0];
        accf[0][1] = (f32x4){bf1, bf1, bf1, bf1};
        accf[1][1] = accf[0][1];
        gpass32<2>(U, Blin, lane, wave * 2, accf);
        // F spill
#pragma unroll
        for (int m = 0; m < 2; ++m)
#pragma unroll
            for (int jj = 0; jj < 2; ++jj) {
                const int col = (wave * 2 + jj) * 16 + la;
#pragma unroll
                for (int r = 0; r < 4; ++r) {
                    const int row = m * 16 + kg * 4 + r;
                    U[FBASE + row * FS + col] = f2bf(accf[m][jj][r]);
                }
            }
    }

    // ---- c prefetch half 1 (flies under IOU GEMM) ----
    short4v c0b, c1b;
    float n2b;
    {
        const int c10 = cc_lds[16 + nd0][0];
        const int c11 = cc_lds[16 + nd0][1];
        const f32x4 t0 = *(const f32x4*)(c_src + (size_t)c10 * 128 + h0q);
        const f32x4 t1 = *(const f32x4*)(c_src + (size_t)c11 * 128 + h0q);
        n2b = dot4(t0);
        c0b = pack4(t0);
        c1b = pack4(t1);
    }
    __syncthreads();   // B2: F visible; A intact

    // ---------- GEMM-IOU: cols 256..639 ----------
    f32x4 accio[2][3];
#pragma unroll
    for (int m = 0; m < 2; ++m)
#pragma unroll
        for (int jj = 0; jj < 3; ++jj) accio[m][jj] = (f32x4){0.f, 0.f, 0.f, 0.f};
    gpass32<3>(U, Blin, lane, 16 + wave * 3, accio);

    // ---------- part 1: forget gates + weighted cell sum (two halves) ----------
    float csr[2][4], s_v[2];
#pragma unroll
    for (int p = 0; p < 2; ++p) {
        const int nd = p * 16 + nd0;
        const short4v c0v = p ? c0b : c0a;
        const short4v c1v = p ? c1b : c1a;
        const short4v yf0 = *(const short4v*)&U[FBASE + nd * FS + h0q];
        const short4v yf1 = *(const short4v*)&U[FBASE + nd * FS + 128 + h0q];
        float c0n2 = wsum32(p ? n2b : n2a);
        float cs[4];
        float csn2 = 0.f;
#pragma unroll
        for (int e = 0; e < 4; ++e) {
            const float f0 = sigm(bf2f(yf0[e]));   // b_f folded into Y
            const float f1 = sigm(bf2f(yf1[e]));
            const float v = f0 * bf2f(c0v[e]) + f1 * bf2f(c1v[e]);
            cs[e] = v;
            csn2 += v * v;
        }
        csn2 = wsum32(csn2);
        const float rs = sc_c * sqrtf(c0n2) / fmaxf(sqrtf(csn2), EPSN);
#pragma unroll
        for (int e = 0; e < 4; ++e) csr[p][e] = cs[e] * rs;
        s_v[p] = sc_iou * sqrtf(iou_n2[nd]) / fmaxf(sqrtf(h_n2[nd]), EPSN);
    }
    __syncthreads();   // B3: F reads + all A reads done

    // ---------- IOU spill (overlays A + dead F rows) ----------
#pragma unroll
    for (int m = 0; m < 2; ++m)
#pragma unroll
        for (int jj = 0; jj < 3; ++jj) {
            const int col = (wave * 3 + jj) * 16 + la;
#pragma unroll
            for (int r = 0; r < 4; ++r) {
                const int row = m * 16 + kg * 4 + r;
                U[row * IS + col] = f2bf(accio[m][jj][r]);
            }
        }
    __syncthreads();   // B4

    // ---------- part 2: i/o/u gates -> h, c (two halves) ----------
    const f32x4 bi0 = *(const f32x4*)(b_iou + h0q);
    const f32x4 bi1 = *(const f32x4*)(b_iou + 128 + h0q);
    const f32x4 bi2 = *(const f32x4*)(b_iou + 256 + h0q);
#pragma unroll
    for (int p = 0; p < 2; ++p) {
        const int nd = p * 16 + nd0;
        const size_t node = nb0 + nd;
        const short4v yi = *(const short4v*)&U[nd * IS + h0q];
        const short4v yo = *(const short4v*)&U[nd * IS + 128 + h0q];
        const short4v yu = *(const short4v*)&U[nd * IS + 256 + h0q];
        f32x4 outh, outc;
#pragma unroll
        for (int e = 0; e < 4; ++e) {
            const float iv = bf2f(yi[e]) * s_v[p] + ((const float*)&bi0)[e];
            const float ov = bf2f(yo[e]) * s_v[p] + ((const float*)&bi1)[e];
            const float uv = bf2f(yu[e]) * s_v[p] + ((const float*)&bi2)[e];
            const float cval = sigm(iv) * tanh_fast(uv) + csr[p][e];
            const float hval = sigm(ov) * tanh_fast(cval);
            ((float*)&outh)[e] = hval;
            ((float*)&outc)[e] = cval;
        }
        // output is written once, never re-read -> nontemporal stores
        __builtin_nontemporal_store(outh, (f32x4*)(out + node * 256 + h0q));
        __builtin_nontemporal_store(outc, (f32x4*)(out + node * 256 + 128 + h0q));
    }
}

extern "C" void kernel_launch(void* const* d_in, const int* in_sizes, int n_in,
                              void* d_out, int out_size, void* d_ws, size_t ws_size,
                              hipStream_t stream) {
    const float* h_src = (const float*)d_in[0];
    const float* c_src = (const float*)d_in[1];
    const float* iou = (const float*)d_in[2];
    const int* cidx = (const int*)d_in[3];
    const float* W_f = (const float*)d_in[4];
    const float* b_f = (const float*)d_in[5];
    const float* W_iou = (const float*)d_in[6];
    const float* b_iou = (const float*)d_in[7];
    const float* s_iou = (const float*)d_in[8];
    const float* s_c = (const float*)d_in[9];
    float* out = (float*)d_out;
    short* Blin = (short*)d_ws;

    const int N = in_sizes[3] / 2;        // 200000
    const int ntiles = N / TN;            // 6250
    hipLaunchKernelGGL(prep_B, dim3(80), dim3(256), 0, stream, W_f, W_iou, Blin);
    hipLaunchKernelGGL(tree_fused, dim3(ntiles), dim3(512), 0, stream,
                       h_src, c_src, iou, cidx, b_f, b_iou, s_iou, s_c, Blin, out);
}